// Round 3
// baseline (852.708 us; speedup 1.0000x reference)
//
#include <hip/hip_runtime.h>
#include <hip/hip_bf16.h>

#define BSZ 32
#define TT 50
#define TS 49

// ---- ws layout (float offsets) ----
#define OFF_VQ    0u        // 100
#define OFF_VK    128u      // 100
#define OFF_SC    256u      // [cq, ck, bw, w1, w2]
#define OFF_BIHH  288u      // 400 (b_ih + b_hh)
#define OFF_GPRE  704u      // 32*49*400 = 627200
#define OFF_QL    627904u   // 32*49*8 = 12544
#define OFF_IDX   640448u   // 32*49*10 ints = 15680
#define OFF_NV    656128u   // 32*49 ints = 1568
#define OFF_QSC   657696u   // 32*49*500 = 784000 -> end 1441696 floats (~5.77 MB)

#define RLF(v,l) __uint_as_float(__builtin_amdgcn_readlane(__float_as_uint(v), (l)))

__device__ __forceinline__ float tanh_fast(float x) {
    float e = __expf(2.f * x);
    return 1.f - __fdividef(2.f, e + 1.f);   // safe at e=inf (->1) and e=0 (->-1)
}
__device__ __forceinline__ float sigm_fast(float x) {
    return __fdividef(1.f, 1.f + __expf(-x));
}

__device__ __forceinline__ float dot100(const float* __restrict__ w, const float* __restrict__ x) {
    float acc = 0.f;
    for (int k = 0; k < 100; k += 4) {
        float4 a = *(const float4*)(w + k);
        float4 b = *(const float4*)(x + k);
        acc += a.x*b.x + a.y*b.y + a.z*b.z + a.w*b.w;
    }
    return acc;
}

// ---------------- prep kernel ----------------
__global__ __launch_bounds__(256) void kprep(
    const float* __restrict__ wq, const float* __restrict__ bq,
    const float* __restrict__ wk, const float* __restrict__ bk,
    const float* __restrict__ ww, const float* __restrict__ bw,
    const float* __restrict__ w1, const float* __restrict__ w2,
    const float* __restrict__ bih, const float* __restrict__ bhh,
    float* __restrict__ WS)
{
    int tid = threadIdx.x;
    for (int i = tid; i < 400; i += 256) WS[OFF_BIHH + i] = bih[i] + bhh[i];
    if (tid < 100) {
        float a1 = 0.f, a2 = 0.f;
        for (int d = 0; d < 100; ++d) {
            a1 += ww[d]       * wq[d*100 + tid];
            a2 += ww[100 + d] * wk[d*100 + tid];
        }
        WS[OFF_VQ + tid] = a1;
        WS[OFF_VK + tid] = a2;
    }
    if (tid == 0) {
        float cq = 0.f, ck = 0.f;
        for (int d = 0; d < 100; ++d) {
            cq += bq[d] * ww[d];
            ck += bk[d] * ww[100 + d];
        }
        WS[OFF_SC + 0] = cq;
        WS[OFF_SC + 1] = ck;
        WS[OFF_SC + 2] = bw[0];
        WS[OFF_SC + 3] = w1[0];
        WS[OFF_SC + 4] = w2[0];
    }
}

// ---------------- aggregation (register-tiled GEMVs) ----------------
__device__ __forceinline__ void aggregate(
    int root, const int* __restrict__ tabA, const int* __restrict__ tabB,
    const float* __restrict__ embE, const float* __restrict__ embO,
    const float* __restrict__ aggw, const float* __restrict__ aggb,
    const float* __restrict__ wlast, const float* __restrict__ blast,
    float* b2in, float* x1, float* s2, float* v1a, float* v1b,
    float* x0, float* v0a, float* v0b,
    int* n1, int* n2, int* n3, float* outE, int tid)
{
    if (tid < 6) n1[tid] = tabA[root*6 + tid];
    __syncthreads();
    if (tid < 36) n2[tid] = tabB[n1[tid/6]*6 + (tid % 6)];
    __syncthreads();
    for (int i = tid; i < 216; i += 256) n3[i] = tabA[n2[i/6]*6 + (i % 6)];
    __syncthreads();
    // stage inputs (pitch 108 to break bank conflicts)
    for (int e = tid; e < 3600; e += 256) {
        int v = e / 100, d = e - v*100;
        float acc = embE[(size_t)n2[v]*100 + d];
        float s3 = 0.f;
        const int* p = n3 + v*6;
        for (int c = 0; c < 6; ++c) s3 += embO[(size_t)p[c]*100 + d];
        b2in[v*108 + d] = acc + s3 * (1.f/6.f);
    }
    for (int e = tid; e < 600; e += 256) {
        int a = e / 100, d = e - a*100;
        float acc = embO[(size_t)n1[a]*100 + d];
        float s = 0.f;
        for (int c = 0; c < 6; ++c) s += embE[(size_t)n2[a*6 + c]*100 + d];
        x1[a*108 + d] = acc + s * (1.f/6.f);
    }
    for (int d = tid; d < 100; d += 256) {
        float acc = embE[(size_t)root*100 + d];
        float s = 0.f;
        for (int a = 0; a < 6; ++a) s += embO[(size_t)n1[a]*100 + d];
        x0[d] = acc + s * (1.f/6.f);
    }
    __syncthreads();
    // ---- i=0 pass: j=2 (sum of 6 tanh dots), j=1, j=0 ----
    if (tid < 150) {
        int dblk = tid / 6, a = tid % 6, d0 = dblk*4;
        const float* w2 = aggw + 20000 + d0*100;
        float o0=0.f,o1=0.f,o2=0.f,o3=0.f;
        for (int c = 0; c < 6; ++c) {
            const float* xr = b2in + (a*6 + c)*108;
            float p0=0.f,p1=0.f,p2=0.f,p3=0.f;
            #pragma unroll
            for (int j = 0; j < 25; ++j) {
                float4 x  = *(const float4*)(xr + 4*j);
                float4 r0 = *(const float4*)(w2 + 4*j);
                float4 r1 = *(const float4*)(w2 + 100 + 4*j);
                float4 r2 = *(const float4*)(w2 + 200 + 4*j);
                float4 r3 = *(const float4*)(w2 + 300 + 4*j);
                p0 += r0.x*x.x + r0.y*x.y + r0.z*x.z + r0.w*x.w;
                p1 += r1.x*x.x + r1.y*x.y + r1.z*x.z + r1.w*x.w;
                p2 += r2.x*x.x + r2.y*x.y + r2.z*x.z + r2.w*x.w;
                p3 += r3.x*x.x + r3.y*x.y + r3.z*x.z + r3.w*x.w;
            }
            o0 += tanh_fast(aggb[200 + d0 + 0] + p0);
            o1 += tanh_fast(aggb[200 + d0 + 1] + p1);
            o2 += tanh_fast(aggb[200 + d0 + 2] + p2);
            o3 += tanh_fast(aggb[200 + d0 + 3] + p3);
        }
        s2[a*100 + d0 + 0] = o0; s2[a*100 + d0 + 1] = o1;
        s2[a*100 + d0 + 2] = o2; s2[a*100 + d0 + 3] = o3;
        // j=1
        const float* w1p = aggw + 10000 + d0*100;
        const float* xr = x1 + a*108;
        float p0=0.f,p1=0.f,p2=0.f,p3=0.f;
        #pragma unroll
        for (int j = 0; j < 25; ++j) {
            float4 x  = *(const float4*)(xr + 4*j);
            float4 r0 = *(const float4*)(w1p + 4*j);
            float4 r1 = *(const float4*)(w1p + 100 + 4*j);
            float4 r2 = *(const float4*)(w1p + 200 + 4*j);
            float4 r3 = *(const float4*)(w1p + 300 + 4*j);
            p0 += r0.x*x.x + r0.y*x.y + r0.z*x.z + r0.w*x.w;
            p1 += r1.x*x.x + r1.y*x.y + r1.z*x.z + r1.w*x.w;
            p2 += r2.x*x.x + r2.y*x.y + r2.z*x.z + r2.w*x.w;
            p3 += r3.x*x.x + r3.y*x.y + r3.z*x.z + r3.w*x.w;
        }
        v1a[a*100 + d0 + 0] = tanh_fast(aggb[100 + d0 + 0] + p0);
        v1a[a*100 + d0 + 1] = tanh_fast(aggb[100 + d0 + 1] + p1);
        v1a[a*100 + d0 + 2] = tanh_fast(aggb[100 + d0 + 2] + p2);
        v1a[a*100 + d0 + 3] = tanh_fast(aggb[100 + d0 + 3] + p3);
    } else if (tid >= 150 && tid < 250) {
        int d = tid - 150;
        v0a[d] = tanh_fast(aggb[d] + dot100(aggw + d*100, x0));
    }
    __syncthreads();
    // rebuild i=1 inputs
    for (int e = tid; e < 600; e += 256) {
        int a = e / 100, d = e - a*100;
        x1[a*108 + d] = v1a[a*100 + d] + s2[a*100 + d]*(1.f/6.f);
    }
    for (int d = tid; d < 100; d += 256) {
        float s = 0.f;
        for (int a = 0; a < 6; ++a) s += v1a[a*100 + d];
        x0[d] = v0a[d] + s*(1.f/6.f);
    }
    __syncthreads();
    // ---- i=1 pass ----
    if (tid < 150) {
        int dblk = tid / 6, a = tid % 6, d0 = dblk*4;
        const float* w1p = aggw + 10000 + d0*100;
        const float* xr = x1 + a*108;
        float p0=0.f,p1=0.f,p2=0.f,p3=0.f;
        #pragma unroll
        for (int j = 0; j < 25; ++j) {
            float4 x  = *(const float4*)(xr + 4*j);
            float4 r0 = *(const float4*)(w1p + 4*j);
            float4 r1 = *(const float4*)(w1p + 100 + 4*j);
            float4 r2 = *(const float4*)(w1p + 200 + 4*j);
            float4 r3 = *(const float4*)(w1p + 300 + 4*j);
            p0 += r0.x*x.x + r0.y*x.y + r0.z*x.z + r0.w*x.w;
            p1 += r1.x*x.x + r1.y*x.y + r1.z*x.z + r1.w*x.w;
            p2 += r2.x*x.x + r2.y*x.y + r2.z*x.z + r2.w*x.w;
            p3 += r3.x*x.x + r3.y*x.y + r3.z*x.z + r3.w*x.w;
        }
        v1b[a*100 + d0 + 0] = tanh_fast(aggb[100 + d0 + 0] + p0);
        v1b[a*100 + d0 + 1] = tanh_fast(aggb[100 + d0 + 1] + p1);
        v1b[a*100 + d0 + 2] = tanh_fast(aggb[100 + d0 + 2] + p2);
        v1b[a*100 + d0 + 3] = tanh_fast(aggb[100 + d0 + 3] + p3);
    } else if (tid >= 150 && tid < 250) {
        int d = tid - 150;
        v0b[d] = tanh_fast(aggb[d] + dot100(aggw + d*100, x0));
    }
    __syncthreads();
    // i=2 input
    for (int d = tid; d < 100; d += 256) {
        float s = 0.f;
        for (int a = 0; a < 6; ++a) s += v1b[a*100 + d];
        x0[d] = v0b[d] + s*(1.f/6.f);
    }
    __syncthreads();
    if (tid < 100)
        v0a[tid] = tanh_fast(aggb[tid] + dot100(aggw + tid*100, x0));
    __syncthreads();
    if (tid < 100)
        outE[tid] = tanh_fast(blast[tid] + dot100(wlast + tid*100, v0a));
}

// ---------------- per-(b,t) parallel kernel ----------------
__global__ __launch_bounds__(256) void kmain(
    const int* __restrict__ user, const int* __restrict__ question, const int* __restrict__ response,
    const int* __restrict__ mask, const int* __restrict__ qnbr, const int* __restrict__ snbr,
    const int* __restrict__ unbr, const int* __restrict__ qnbr2, const int* __restrict__ qsidx,
    const float* __restrict__ embQ, const float* __restrict__ embQ2, const float* __restrict__ embS,
    const float* __restrict__ embU, const float* __restrict__ embR,
    const float* __restrict__ aggw, const float* __restrict__ aggb,
    const float* __restrict__ wlast, const float* __restrict__ blast,
    const float* __restrict__ wfus, const float* __restrict__ bfus,
    const float* __restrict__ wih,
    float* __restrict__ WS)
{
    int bid = blockIdx.x;
    int b = bid / TS, t = bid - b*TS;
    int tid = threadIdx.x;

    __shared__ __align__(16) float sB2in[36*108];
    __shared__ __align__(16) float sX1[6*108];
    __shared__ float sS2[600], sV1a[600], sV1b[600];
    __shared__ __align__(16) float sX0[104], sV0a[104], sV0b[104];
    __shared__ __align__(16) float sE1[104], sE2[104];
    __shared__ __align__(16) float sEIN[200], sET[104], sEQN[104];
    __shared__ float sQSCm[500], sScore[52];
    __shared__ int sN1[8], sN2[36], sN3[216];

    int q_t = question[b*TT + t];
    int u_t = user[b*TT + t];
    int r_t = response[b*TT + t];
    int mm  = mask[b*TT + t];

    if (mm == 1) {
        aggregate(q_t, qnbr, snbr, embQ, embS, aggw, aggb, wlast, blast,
                  sB2in, sX1, sS2, sV1a, sV1b, sX0, sV0a, sV0b, sN1, sN2, sN3, sE1, tid);
        __syncthreads();
        aggregate(u_t, unbr, qnbr2, embU, embQ2, aggw, aggb, wlast, blast,
                  sB2in, sX1, sS2, sV1a, sV1b, sX0, sV0a, sV0b, sN1, sN2, sN3, sE2, tid);
    } else {
        for (int d = tid; d < 100; d += 256) {
            sE1[d] = embQ[(size_t)q_t*100 + d];
            sE2[d] = embQ2[(size_t)q_t*100 + d];
        }
    }
    __syncthreads();
    float w1 = WS[OFF_SC + 3], w2s = WS[OFF_SC + 4];
    for (int d = tid; d < 100; d += 256) {
        sEIN[d]       = w1*sE1[d] + w2s*sE2[d];
        sEIN[100 + d] = embR[r_t*100 + d];
    }
    __syncthreads();
    for (int o = tid; o < 100; o += 256) {
        float acc = bfus[o];
        const float* wr = wfus + o*200;
        for (int k = 0; k < 200; k += 4) {
            float4 a = *(const float4*)(wr + k);
            float4 x = *(const float4*)(sEIN + k);
            acc += a.x*x.x + a.y*x.y + a.z*x.z + a.w*x.w;
        }
        sET[o] = fmaxf(acc, 0.f);
    }
    __syncthreads();
    size_t bt = (size_t)b*TS + t;
    for (int o = tid; o < 400; o += 256)
        WS[OFF_GPRE + bt*400 + o] = WS[OFF_BIHH + o] + dot100(wih + o*100, sET);

    // ---- predict-side precompute for step t (uses question[t+1]) ----
    int qn = question[b*TT + t + 1];
    for (int d = tid; d < 100; d += 256) sEQN[d] = embQ[(size_t)qn*100 + d];
    __syncthreads();
    for (int i = tid; i < 500; i += 256) {
        int q = i / 100, d = i - q*100;
        float val = (q == 0) ? sEQN[d] : embS[(size_t)qsidx[qn*4 + (q-1)]*100 + d];
        sQSCm[i] = val;
        WS[OFF_QSC + bt*500 + i] = val;
    }
    for (int tp = tid; tp < 50; tp += 256) {
        if (tp < t) {
            int qq = question[b*TT + tp];
            float acc = 0.f;
            for (int k = 0; k < 100; ++k) acc += embQ[(size_t)qq*100 + k] * sEQN[k];
            sScore[tp] = acc;
        }
    }
    __syncthreads();
    if (tid < 5) {
        float acc = WS[OFF_SC + 0];
        for (int k = 0; k < 100; ++k) acc += sQSCm[tid*100 + k] * WS[OFF_VQ + k];
        WS[OFF_QL + bt*8 + tid] = acc;
    }
    if (tid == 64) {
        int nv = t < 10 ? t : 10;
        ((int*)(WS + OFF_NV))[bt] = nv;
        int* idxp = (int*)(WS + OFF_IDX) + bt*10;
        unsigned long long taken = 0ull;
        for (int p = 0; p < 10; ++p) {
            int bi = 0;
            if (p < nv) {
                float best = -3.0e38f;
                for (int tp2 = 0; tp2 < t; ++tp2) {
                    if (!((taken >> tp2) & 1ull) && sScore[tp2] > best) { best = sScore[tp2]; bi = tp2; }
                }
                taken |= (1ull << bi);
            }
            idxp[p] = bi;
        }
    }
}

// ---------------- sequential scan kernel (one block per batch element) ----------------
__global__ __launch_bounds__(512, 2) void kseq(
    const int* __restrict__ mask, const float* __restrict__ whh,
    const float* __restrict__ WS, float* __restrict__ out)
{
    int b = blockIdx.x, tid = threadIdx.x;
    __shared__ float sSH[TT*100];
    __shared__ float sH[104], sC[104], sG[400], sVKl[104];
    __shared__ float sQSCb[2][512];
    __shared__ float sQL5b[2][8];
    __shared__ float sKL[16], sGv[64];
    __shared__ int sIdxb[2][16];
    __shared__ int sNvb[2];
    __shared__ int sMask[52];

    const float* gGPRE = WS + OFF_GPRE;
    const float* gQL   = WS + OFF_QL;
    const float* gQSC  = WS + OFF_QSC;
    const int*   gIDX  = (const int*)(WS + OFF_IDX);
    const int*   gNV   = (const int*)(WS + OFF_NV);

    // W_hh rows resident in VGPRs (one gate per thread)
    float4 wv[25];
    if (tid < 400) {
        #pragma unroll
        for (int j = 0; j < 25; ++j) wv[j] = *(const float4*)(whh + tid*100 + 4*j);
    }
    for (int i = tid; i < 100; i += 512) { sH[i] = 0.f; sC[i] = 0.f; sVKl[i] = WS[OFF_VK + i]; }
    if (tid < 50) sMask[tid] = mask[b*TT + tid];
    {
        size_t bt0 = (size_t)b*TS;
        for (int i = tid; i < 500; i += 512) sQSCb[0][i] = gQSC[bt0*500 + i];
        if (tid < 10) sIdxb[0][tid] = gIDX[bt0*10 + tid];
        if (tid < 5)  sQL5b[0][tid] = gQL[bt0*8 + tid];
        if (tid == 0) { sNvb[0] = gNV[bt0]; out[b*TT] = 0.5f; }
    }
    float ck = WS[OFF_SC + 1], bw = WS[OFF_SC + 2];
    __syncthreads();

    for (int t = 0; t < TS; ++t) {
        size_t bt = (size_t)b*TS + t;
        int cb = t & 1, nb = cb ^ 1;
        int lane = tid & 63;
        // distribute h across every wave's lanes (full-exec loads)
        float hA = sH[lane];
        float hB = sH[64 + (lane % 36)];

        if (tid < 400) {
            // -------- gates: 100-FMA chain with readlane broadcast --------
            float gp = gGPRE[bt*400 + tid];
            float a0 = 0.f, a1 = 0.f, a2 = 0.f, a3 = 0.f;
            #pragma unroll
            for (int j = 0; j < 25; ++j) {
                const int kb = 4*j;
                float h0, h1, h2, h3;
                if (kb < 64) {
                    h0 = RLF(hA, kb);   h1 = RLF(hA, kb+1);
                    h2 = RLF(hA, kb+2); h3 = RLF(hA, kb+3);
                } else {
                    h0 = RLF(hB, kb-64); h1 = RLF(hB, kb-63);
                    h2 = RLF(hB, kb-62); h3 = RLF(hB, kb-61);
                }
                a0 = fmaf(h0, wv[j].x, a0);
                a1 = fmaf(h1, wv[j].y, a1);
                a2 = fmaf(h2, wv[j].z, a2);
                a3 = fmaf(h3, wv[j].w, a3);
            }
            sG[tid] = (a0 + a1) + (a2 + a3) + gp;
        } else if (tid >= 448) {
            // -------- wave 7: prefetch next-step data + h-independent dots --------
            int l = tid - 448;
            int tn = t + 1;
            float pf[8]; float pql = 0.f; int pidx = 0, pnv = 0;
            int base = l*8;
            if (tn < TS) {
                size_t btn = (size_t)b*TS + tn;
                const float* src = gQSC + btn*500;
                #pragma unroll
                for (int j = 0; j < 8; ++j) pf[j] = (base + j < 500) ? src[base + j] : 0.f;
                if (l < 10) pidx = gIDX[btn*10 + l];
                if (l < 5)  pql  = gQL[btn*8 + l];
                if (l == 0) pnv  = gNV[btn];
            }
            // old-state dots: kl[s], g[q][s] for s=1..nv (use history rows, QSC of step t)
            int nv = sNvb[cb];
            int grp = l >> 4, k0 = l & 15;
            for (int p = 0; p < 15; ++p) {
                int id = p*4 + grp;           // 0..59
                int s, q = 0; bool isKL;
                if (id < 10) { s = id + 1; isKL = true; }
                else { int r = id - 10; q = r / 10; s = (r % 10) + 1; isKL = false; }
                float acc = 0.f;
                bool on = (s <= nv);
                if (on) {
                    int row = sIdxb[cb][s-1];
                    const float* st = sSH + row*100;
                    const float* xp = isKL ? sVKl : (&sQSCb[cb][q*100]);
                    #pragma unroll
                    for (int j = 0; j < 7; ++j) { int k = k0 + 16*j; if (k < 100) acc = fmaf(st[k], xp[k], acc); }
                }
                acc += __shfl_xor(acc, 1); acc += __shfl_xor(acc, 2);
                acc += __shfl_xor(acc, 4); acc += __shfl_xor(acc, 8);
                if (on && k0 == 0) { if (isKL) sKL[s] = acc + ck; else sGv[q*11 + s] = acc; }
            }
            // commit prefetched next-step buffers
            if (tn < TS) {
                #pragma unroll
                for (int j = 0; j < 8; ++j) if (base + j < 500) sQSCb[nb][base + j] = pf[j];
                if (l < 10) sIdxb[nb][l] = pidx;
                if (l < 5)  sQL5b[nb][l] = pql;
                if (l == 0) sNvb[nb] = pnv;
            }
        }
        __syncthreads();
        // -------- LSTM pointwise --------
        int mm = sMask[t];
        if (tid < 100) {
            float gi = sG[tid], gf = sG[100+tid], gg = sG[200+tid], go = sG[300+tid];
            float c2 = sigm_fast(gf)*sC[tid] + sigm_fast(gi)*tanh_fast(gg);
            float h2 = sigm_fast(go)*tanh_fast(c2);
            if (mm == 1) { sH[tid] = h2; sC[tid] = c2; }
            sSH[t*100 + tid] = sH[tid];
        }
        __syncthreads();
        // -------- h-dependent dots: kl[0], g[q][0] --------
        if (tid < 96) {
            int id = tid >> 4, k0 = tid & 15;
            const float* st = sH;
            const float* xp = (id == 0) ? sVKl : (&sQSCb[cb][(id-1)*100]);
            float acc = 0.f;
            #pragma unroll
            for (int j = 0; j < 7; ++j) { int k = k0 + 16*j; if (k < 100) acc = fmaf(st[k], xp[k], acc); }
            acc += __shfl_xor(acc, 1); acc += __shfl_xor(acc, 2);
            acc += __shfl_xor(acc, 4); acc += __shfl_xor(acc, 8);
            if (k0 == 0) { if (id == 0) sKL[0] = acc + ck; else sGv[(id-1)*11 + 0] = acc; }
        }
        __syncthreads();
        // -------- softmax + output --------
        if (tid < 64) {
            int nst = sNvb[cb] + 1;
            int q = tid / 11, s = tid - q*11;
            bool valid = (tid < 55) && (s < nst);
            float lg = valid ? (sQL5b[cb][q] + sKL[s] + bw) : -3.0e38f;
            float mx = lg;
            #pragma unroll
            for (int m = 1; m < 64; m <<= 1) mx = fmaxf(mx, __shfl_xor(mx, m));
            float e  = valid ? __expf(lg - mx) : 0.f;
            float gv = valid ? sGv[q*11 + s] : 0.f;
            float se = e, sg = e*gv;
            #pragma unroll
            for (int m = 1; m < 64; m <<= 1) { se += __shfl_xor(se, m); sg += __shfl_xor(sg, m); }
            if (tid == 0) out[b*TT + t + 1] = __fdividef(1.f, 1.f + __expf(-__fdividef(sg, se)));
        }
        __syncthreads();
    }
}

extern "C" void kernel_launch(void* const* d_in, const int* in_sizes, int n_in,
                              void* d_out, int out_size, void* d_ws, size_t ws_size,
                              hipStream_t stream) {
    const int* user      = (const int*)d_in[0];
    const int* question  = (const int*)d_in[1];
    const int* response  = (const int*)d_in[2];
    const int* mask      = (const int*)d_in[3];
    const int* qnbr      = (const int*)d_in[4];
    const int* snbr      = (const int*)d_in[5];
    const int* unbr      = (const int*)d_in[6];
    const int* qnbr2     = (const int*)d_in[7];
    const int* qsidx     = (const int*)d_in[8];
    const float* embQ    = (const float*)d_in[9];
    const float* embQ2   = (const float*)d_in[10];
    const float* embS    = (const float*)d_in[11];
    const float* embU    = (const float*)d_in[12];
    const float* embR    = (const float*)d_in[13];
    const float* w1      = (const float*)d_in[14];
    const float* w2      = (const float*)d_in[15];
    const float* wih     = (const float*)d_in[16];
    const float* whh     = (const float*)d_in[17];
    const float* bih     = (const float*)d_in[18];
    const float* bhh     = (const float*)d_in[19];
    const float* aggw    = (const float*)d_in[20];
    const float* aggb    = (const float*)d_in[21];
    const float* wlast   = (const float*)d_in[22];
    const float* blast   = (const float*)d_in[23];
    const float* wq      = (const float*)d_in[24];
    const float* bq      = (const float*)d_in[25];
    const float* wk      = (const float*)d_in[26];
    const float* bk      = (const float*)d_in[27];
    const float* ww      = (const float*)d_in[28];
    const float* bwp     = (const float*)d_in[29];
    const float* wfus    = (const float*)d_in[30];
    const float* bfus    = (const float*)d_in[31];
    float* WS = (float*)d_ws;
    float* out = (float*)d_out;

    hipLaunchKernelGGL(kprep, dim3(1), dim3(256), 0, stream,
                       wq, bq, wk, bk, ww, bwp, w1, w2, bih, bhh, WS);
    hipLaunchKernelGGL(kmain, dim3(BSZ*TS), dim3(256), 0, stream,
                       user, question, response, mask, qnbr, snbr, unbr, qnbr2, qsidx,
                       embQ, embQ2, embS, embU, embR,
                       aggw, aggb, wlast, blast, wfus, bfus, wih, WS);
    hipLaunchKernelGGL(kseq, dim3(BSZ), dim3(512), 0, stream,
                       mask, whh, WS, out);
}

// Round 4
// 489.225 us; speedup vs baseline: 1.7430x; 1.7430x over previous
//
#include <hip/hip_runtime.h>
#include <hip/hip_bf16.h>

#define BSZ 32
#define TT 50
#define TS 49

// ---- ws layout (float offsets) ----
#define OFF_VQ    0u        // 100
#define OFF_VK    128u      // 100
#define OFF_SC    256u      // [cq, ck, bw, w1, w2]
#define OFF_BIHH  288u      // 400 (b_ih + b_hh)
#define OFF_GPRE  704u      // 32*49*400 = 627200
#define OFF_QL    627904u   // 32*49*8 = 12544
#define OFF_IDX   640448u   // 32*49*10 ints = 15680
#define OFF_NV    656128u   // 32*49 ints = 1568
#define OFF_QSC   657696u   // 32*49*500 = 784000 -> 1441696
#define OFF_E1    1441696u  // 32*49*100 = 156800 -> 1598496
#define OFF_E2    1598496u  // 156800 -> end 1755296 floats (~7.02 MB)

#define RLF(v,l) __uint_as_float(__builtin_amdgcn_readlane(__float_as_uint(v), (l)))

__device__ __forceinline__ float tanh_fast(float x) {
    float e = __expf(2.f * x);
    return 1.f - __fdividef(2.f, e + 1.f);
}
__device__ __forceinline__ float sigm_fast(float x) {
    return __fdividef(1.f, 1.f + __expf(-x));
}
__device__ __forceinline__ float dot4(float4 a, float4 b) {
    return a.x*b.x + a.y*b.y + a.z*b.z + a.w*b.w;
}
__device__ __forceinline__ float dot100(const float* __restrict__ w, const float* __restrict__ x) {
    float acc = 0.f;
    for (int k = 0; k < 100; k += 4)
        acc += dot4(*(const float4*)(w + k), *(const float4*)(x + k));
    return acc;
}

// ---------------- prep kernel ----------------
__global__ __launch_bounds__(256) void kprep(
    const float* __restrict__ wq, const float* __restrict__ bq,
    const float* __restrict__ wk, const float* __restrict__ bk,
    const float* __restrict__ ww, const float* __restrict__ bw,
    const float* __restrict__ w1, const float* __restrict__ w2,
    const float* __restrict__ bih, const float* __restrict__ bhh,
    float* __restrict__ WS)
{
    int tid = threadIdx.x;
    for (int i = tid; i < 400; i += 256) WS[OFF_BIHH + i] = bih[i] + bhh[i];
    if (tid < 100) {
        float a1 = 0.f, a2 = 0.f;
        for (int d = 0; d < 100; ++d) {
            a1 += ww[d]       * wq[d*100 + tid];
            a2 += ww[100 + d] * wk[d*100 + tid];
        }
        WS[OFF_VQ + tid] = a1;
        WS[OFF_VK + tid] = a2;
    }
    if (tid == 0) {
        float cq = 0.f, ck = 0.f;
        for (int d = 0; d < 100; ++d) {
            cq += bq[d] * ww[d];
            ck += bk[d] * ww[100 + d];
        }
        WS[OFF_SC + 0] = cq;
        WS[OFF_SC + 1] = ck;
        WS[OFF_SC + 2] = bw[0];
        WS[OFF_SC + 3] = w1[0];
        WS[OFF_SC + 4] = w2[0];
    }
}

// ---------------- one aggregate per block ----------------
__global__ __launch_bounds__(256) void kagg(
    const int* __restrict__ user, const int* __restrict__ question, const int* __restrict__ mask,
    const int* __restrict__ qnbr, const int* __restrict__ snbr,
    const int* __restrict__ unbr, const int* __restrict__ qnbr2,
    const float* __restrict__ embQ, const float* __restrict__ embQ2, const float* __restrict__ embS,
    const float* __restrict__ embU,
    const float* __restrict__ aggw, const float* __restrict__ aggb,
    const float* __restrict__ wlast, const float* __restrict__ blast,
    float* __restrict__ WS)
{
    int bid = blockIdx.x;
    int pair = bid >> 1, which = bid & 1;
    int b = pair / TS, t = pair - b*TS;
    int tid = threadIdx.x;
    int mm = mask[b*TT + t];
    float* outE = WS + (which ? OFF_E2 : OFF_E1) + (size_t)pair*100;

    if (mm != 1) {
        int q_t = question[b*TT + t];
        const float* src = which ? embQ2 : embQ;
        if (tid < 100) outE[tid] = src[(size_t)q_t*100 + tid];
        return;
    }

    int root = which ? user[b*TT + t] : question[b*TT + t];
    const int*   tabA = which ? unbr  : qnbr;
    const int*   tabB = which ? qnbr2 : snbr;
    const float* embE = which ? embU  : embQ;
    const float* embO = which ? embQ2 : embS;

    __shared__ __align__(16) float b2in[36*108];
    __shared__ __align__(16) float x1[6*108];
    __shared__ float s2[600], v1a[600], v1b[600];
    __shared__ __align__(16) float x0[104], v0a[104], v0b[104];
    __shared__ int n1[8], n2[36], n3[216];

    if (tid < 6) n1[tid] = tabA[root*6 + tid];
    __syncthreads();
    if (tid < 36) n2[tid] = tabB[n1[tid/6]*6 + (tid % 6)];
    __syncthreads();
    if (tid < 216) n3[tid] = tabA[n2[tid/6]*6 + (tid % 6)];
    __syncthreads();
    // stage inputs (pitch 108)
    for (int e = tid; e < 3600; e += 256) {
        int v = e / 100, d = e - v*100;
        float acc = embE[(size_t)n2[v]*100 + d];
        float s3 = 0.f;
        const int* p = n3 + v*6;
        for (int c = 0; c < 6; ++c) s3 += embO[(size_t)p[c]*100 + d];
        b2in[v*108 + d] = acc + s3 * (1.f/6.f);
    }
    for (int e = tid; e < 600; e += 256) {
        int a = e / 100, d = e - a*100;
        float acc = embO[(size_t)n1[a]*100 + d];
        float s = 0.f;
        for (int c = 0; c < 6; ++c) s += embE[(size_t)n2[a*6 + c]*100 + d];
        x1[a*108 + d] = acc + s * (1.f/6.f);
    }
    if (tid < 100) {
        float acc = embE[(size_t)root*100 + tid];
        float s = 0.f;
        for (int a = 0; a < 6; ++a) s += embO[(size_t)n1[a]*100 + tid];
        x0[tid] = acc + s * (1.f/6.f);
    }
    __syncthreads();
    // ---- i=0: j=2 (tid<150, 4rowsx6cols), j=1 (tid 150..199, 2x6), j=0 (tid 200..249, 2 rows) ----
    if (tid < 150) {
        int dblk = tid / 6, a = tid % 6, d0 = dblk*4;
        const float* wp = aggw + 20000 + d0*100;
        const float* xb = b2in + a*648;
        float acc[4][6];
        #pragma unroll
        for (int r = 0; r < 4; ++r)
            #pragma unroll
            for (int c = 0; c < 6; ++c) acc[r][c] = 0.f;
        #pragma unroll
        for (int j = 0; j < 25; ++j) {
            float4 r0 = *(const float4*)(wp + 4*j);
            float4 r1 = *(const float4*)(wp + 100 + 4*j);
            float4 r2 = *(const float4*)(wp + 200 + 4*j);
            float4 r3 = *(const float4*)(wp + 300 + 4*j);
            #pragma unroll
            for (int c = 0; c < 6; ++c) {
                float4 x = *(const float4*)(xb + c*108 + 4*j);
                acc[0][c] += dot4(r0, x);
                acc[1][c] += dot4(r1, x);
                acc[2][c] += dot4(r2, x);
                acc[3][c] += dot4(r3, x);
            }
        }
        #pragma unroll
        for (int r = 0; r < 4; ++r) {
            float bia = aggb[200 + d0 + r];
            float o = 0.f;
            #pragma unroll
            for (int c = 0; c < 6; ++c) o += tanh_fast(bia + acc[r][c]);
            s2[a*100 + d0 + r] = o;
        }
    } else if (tid < 200) {
        int d0 = (tid - 150)*2;
        const float* wp = aggw + 10000 + d0*100;
        float acc[2][6];
        #pragma unroll
        for (int r = 0; r < 2; ++r)
            #pragma unroll
            for (int c = 0; c < 6; ++c) acc[r][c] = 0.f;
        #pragma unroll
        for (int j = 0; j < 25; ++j) {
            float4 r0 = *(const float4*)(wp + 4*j);
            float4 r1 = *(const float4*)(wp + 100 + 4*j);
            #pragma unroll
            for (int c = 0; c < 6; ++c) {
                float4 x = *(const float4*)(x1 + c*108 + 4*j);
                acc[0][c] += dot4(r0, x);
                acc[1][c] += dot4(r1, x);
            }
        }
        #pragma unroll
        for (int r = 0; r < 2; ++r)
            #pragma unroll
            for (int c = 0; c < 6; ++c)
                v1a[c*100 + d0 + r] = tanh_fast(aggb[100 + d0 + r] + acc[r][c]);
    } else if (tid < 250) {
        int d0 = (tid - 200)*2;
        const float* wp = aggw + d0*100;
        float a0 = 0.f, a1 = 0.f;
        #pragma unroll
        for (int j = 0; j < 25; ++j) {
            float4 x  = *(const float4*)(x0 + 4*j);
            a0 += dot4(*(const float4*)(wp + 4*j), x);
            a1 += dot4(*(const float4*)(wp + 100 + 4*j), x);
        }
        v0a[d0]   = tanh_fast(aggb[d0] + a0);
        v0a[d0+1] = tanh_fast(aggb[d0+1] + a1);
    }
    __syncthreads();
    // rebuild i=1 inputs
    for (int e = tid; e < 600; e += 256) {
        int a = e / 100, d = e - a*100;
        x1[a*108 + d] = v1a[a*100 + d] + s2[a*100 + d]*(1.f/6.f);
    }
    if (tid < 100) {
        float s = 0.f;
        for (int a = 0; a < 6; ++a) s += v1a[a*100 + tid];
        x0[tid] = v0a[tid] + s*(1.f/6.f);
    }
    __syncthreads();
    // ---- i=1: j=1 (tid<50, 2x6), j=0 (tid 64..113, 2 rows) ----
    if (tid < 50) {
        int d0 = tid*2;
        const float* wp = aggw + 10000 + d0*100;
        float acc[2][6];
        #pragma unroll
        for (int r = 0; r < 2; ++r)
            #pragma unroll
            for (int c = 0; c < 6; ++c) acc[r][c] = 0.f;
        #pragma unroll
        for (int j = 0; j < 25; ++j) {
            float4 r0 = *(const float4*)(wp + 4*j);
            float4 r1 = *(const float4*)(wp + 100 + 4*j);
            #pragma unroll
            for (int c = 0; c < 6; ++c) {
                float4 x = *(const float4*)(x1 + c*108 + 4*j);
                acc[0][c] += dot4(r0, x);
                acc[1][c] += dot4(r1, x);
            }
        }
        #pragma unroll
        for (int r = 0; r < 2; ++r)
            #pragma unroll
            for (int c = 0; c < 6; ++c)
                v1b[c*100 + d0 + r] = tanh_fast(aggb[100 + d0 + r] + acc[r][c]);
    } else if (tid >= 64 && tid < 114) {
        int d0 = (tid - 64)*2;
        const float* wp = aggw + d0*100;
        float a0 = 0.f, a1 = 0.f;
        #pragma unroll
        for (int j = 0; j < 25; ++j) {
            float4 x  = *(const float4*)(x0 + 4*j);
            a0 += dot4(*(const float4*)(wp + 4*j), x);
            a1 += dot4(*(const float4*)(wp + 100 + 4*j), x);
        }
        v0b[d0]   = tanh_fast(aggb[d0] + a0);
        v0b[d0+1] = tanh_fast(aggb[d0+1] + a1);
    }
    __syncthreads();
    // i=2 input
    if (tid < 100) {
        float s = 0.f;
        for (int a = 0; a < 6; ++a) s += v1b[a*100 + tid];
        x0[tid] = v0b[tid] + s*(1.f/6.f);
    }
    __syncthreads();
    if (tid < 50) {
        int d0 = tid*2;
        const float* wp = aggw + d0*100;
        float a0 = 0.f, a1 = 0.f;
        #pragma unroll
        for (int j = 0; j < 25; ++j) {
            float4 x  = *(const float4*)(x0 + 4*j);
            a0 += dot4(*(const float4*)(wp + 4*j), x);
            a1 += dot4(*(const float4*)(wp + 100 + 4*j), x);
        }
        v0a[d0]   = tanh_fast(aggb[d0] + a0);
        v0a[d0+1] = tanh_fast(aggb[d0+1] + a1);
    }
    __syncthreads();
    if (tid < 50) {
        int d0 = tid*2;
        const float* wp = wlast + d0*100;
        float a0 = 0.f, a1 = 0.f;
        #pragma unroll
        for (int j = 0; j < 25; ++j) {
            float4 x  = *(const float4*)(v0a + 4*j);
            a0 += dot4(*(const float4*)(wp + 4*j), x);
            a1 += dot4(*(const float4*)(wp + 100 + 4*j), x);
        }
        outE[d0]   = tanh_fast(blast[d0] + a0);
        outE[d0+1] = tanh_fast(blast[d0+1] + a1);
    }
}

// ---------------- fusion + GPRE + predict-side precompute ----------------
__global__ __launch_bounds__(256) void kfuse(
    const int* __restrict__ question, const int* __restrict__ response,
    const int* __restrict__ qsidx,
    const float* __restrict__ embQ, const float* __restrict__ embS, const float* __restrict__ embR,
    const float* __restrict__ wfus, const float* __restrict__ bfus,
    const float* __restrict__ wih,
    float* __restrict__ WS)
{
    int bid = blockIdx.x;
    int b = bid / TS, t = bid - b*TS;
    int tid = threadIdx.x;
    size_t bt = (size_t)b*TS + t;

    __shared__ __align__(16) float sEIN[200], sET[104], sEQN[104];
    __shared__ float sQSCm[500], sScore[52];

    int r_t = response[b*TT + t];
    int qn  = question[b*TT + t + 1];
    float w1 = WS[OFF_SC + 3], w2s = WS[OFF_SC + 4];
    if (tid < 100)
        sEIN[tid] = w1*WS[OFF_E1 + bt*100 + tid] + w2s*WS[OFF_E2 + bt*100 + tid];
    else if (tid < 200)
        sEIN[tid] = embR[r_t*100 + (tid - 100)];
    __syncthreads();
    if (tid < 100) {
        float acc = bfus[tid];
        const float* wr = wfus + tid*200;
        for (int k = 0; k < 200; k += 4)
            acc += dot4(*(const float4*)(wr + k), *(const float4*)(sEIN + k));
        sET[tid] = fmaxf(acc, 0.f);
    } else if (tid >= 128 && tid < 228) {
        sEQN[tid - 128] = embQ[(size_t)qn*100 + (tid - 128)];
    }
    __syncthreads();
    for (int o = tid; o < 400; o += 256)
        WS[OFF_GPRE + bt*400 + o] = WS[OFF_BIHH + o] + dot100(wih + o*100, sET);
    for (int i = tid; i < 500; i += 256) {
        int q = i / 100, d = i - q*100;
        float val = (q == 0) ? sEQN[d] : embS[(size_t)qsidx[qn*4 + (q-1)]*100 + d];
        sQSCm[i] = val;
        WS[OFF_QSC + bt*500 + i] = val;
    }
    if (tid >= 200 && tid < 200 + TT) {
        int tp = tid - 200;
        if (tp < t) {
            int qq = question[b*TT + tp];
            float acc = 0.f;
            for (int k = 0; k < 100; ++k) acc += embQ[(size_t)qq*100 + k] * sEQN[k];
            sScore[tp] = acc;
        }
    }
    __syncthreads();
    if (tid < 5) {
        float acc = WS[OFF_SC + 0];
        for (int k = 0; k < 100; ++k) acc += sQSCm[tid*100 + k] * WS[OFF_VQ + k];
        WS[OFF_QL + bt*8 + tid] = acc;
    }
    if (tid == 64) {
        int nv = t < 10 ? t : 10;
        ((int*)(WS + OFF_NV))[bt] = nv;
        int* idxp = (int*)(WS + OFF_IDX) + bt*10;
        unsigned long long taken = 0ull;
        for (int p = 0; p < 10; ++p) {
            int bi = 0;
            if (p < nv) {
                float best = -3.0e38f;
                for (int tp2 = 0; tp2 < t; ++tp2) {
                    if (!((taken >> tp2) & 1ull) && sScore[tp2] > best) { best = sScore[tp2]; bi = tp2; }
                }
                taken |= (1ull << bi);
            }
            idxp[p] = bi;
        }
    }
}

// ---------------- sequential scan (one block per batch element) ----------------
__global__ __launch_bounds__(512) void kseq(
    const int* __restrict__ mask, const float* __restrict__ whh,
    const float* __restrict__ WS, float* __restrict__ out)
{
    int b = blockIdx.x, tid = threadIdx.x, lane = tid & 63;
    __shared__ float sQSCall[TS*500];   // 98 KB
    __shared__ float sSH[TS*100];       // 19.6 KB
    __shared__ float sQLall[TS*8];
    __shared__ int   sIdxAll[TS*10];
    __shared__ int   sNvAll[TS];
    __shared__ int   sMask[TT];
    __shared__ float sH[104], sC[104], sG[400], sVKl[104];
    __shared__ float sKL[12], sGv[64];

    const float* gGPRE = WS + OFF_GPRE;
    size_t b0 = (size_t)b*TS;

    // W_hh rows resident in VGPRs (one gate per thread for tid<400)
    float4 wv[25];
    if (tid < 400) {
        #pragma unroll
        for (int j = 0; j < 25; ++j) wv[j] = *(const float4*)(whh + tid*100 + 4*j);
    }
    float gpre = (tid < 400) ? gGPRE[b0*400 + tid] : 0.f;

    for (int i = tid; i < TS*500; i += 512) sQSCall[i] = WS[OFF_QSC + b0*500 + i];
    for (int i = tid; i < TS*8;   i += 512) sQLall[i]  = WS[OFF_QL + b0*8 + i];
    for (int i = tid; i < TS*10;  i += 512) sIdxAll[i] = ((const int*)(WS + OFF_IDX))[b0*10 + i];
    for (int i = tid; i < TS;     i += 512) sNvAll[i]  = ((const int*)(WS + OFF_NV))[b0 + i];
    if (tid < TT) sMask[tid] = mask[b*TT + tid];
    for (int i = tid; i < 104; i += 512) { sH[i] = 0.f; sC[i] = 0.f; sVKl[i] = (i < 100) ? WS[OFF_VK + i] : 0.f; }
    float ck = WS[OFF_SC + 1], bw = WS[OFF_SC + 2];
    if (tid == 0) out[b*TT] = 0.5f;
    __syncthreads();

    for (int t = 0; t < TS; ++t) {
        // prefetch next step's Gpre while computing this step
        float gpre_nx = 0.f;
        if (tid < 400 && t + 1 < TS) gpre_nx = gGPRE[(b0 + t + 1)*400 + tid];

        // -------- gates --------
        float hA = sH[lane];
        float hB = sH[64 + (lane % 36)];
        if (tid < 400) {
            float a0 = 0.f, a1 = 0.f, a2 = 0.f, a3 = 0.f;
            #pragma unroll
            for (int j = 0; j < 25; ++j) {
                const int kb = 4*j;
                float h0, h1, h2, h3;
                if (kb < 64) {
                    h0 = RLF(hA, kb);   h1 = RLF(hA, kb+1);
                    h2 = RLF(hA, kb+2); h3 = RLF(hA, kb+3);
                } else {
                    h0 = RLF(hB, kb-64); h1 = RLF(hB, kb-63);
                    h2 = RLF(hB, kb-62); h3 = RLF(hB, kb-61);
                }
                a0 = fmaf(h0, wv[j].x, a0);
                a1 = fmaf(h1, wv[j].y, a1);
                a2 = fmaf(h2, wv[j].z, a2);
                a3 = fmaf(h3, wv[j].w, a3);
            }
            sG[tid] = (a0 + a1) + (a2 + a3) + gpre;
        }
        __syncthreads();
        // -------- LSTM pointwise --------
        if (tid < 100) {
            int mm = sMask[t];
            float gi = sG[tid], gf = sG[100+tid], gg = sG[200+tid], go = sG[300+tid];
            float c2 = sigm_fast(gf)*sC[tid] + sigm_fast(gi)*tanh_fast(gg);
            float h2 = sigm_fast(go)*tanh_fast(c2);
            if (mm == 1) { sH[tid] = h2; sC[tid] = c2; }
            sSH[t*100 + tid] = sH[tid];
        }
        __syncthreads();
        // -------- 66 attention dots, 16 lanes each, 3 passes --------
        int nv = sNvAll[t];
        int k0 = tid & 15, slot = tid >> 4;
        const float* xq = sQSCall + t*500;
        #pragma unroll
        for (int p = 0; p < 3; ++p) {
            int id = p*32 + slot;          // 0..95; valid < 66
            float acc = 0.f;
            bool on = false, isKL = false; int q = 0, s = 0;
            if (id < 66) {
                isKL = id < 11;
                if (isKL) s = id; else { q = (id - 11) / 11; s = (id - 11) % 11; }
                if (s <= nv) {
                    on = true;
                    const float* st = (s == 0) ? sH : (sSH + sIdxAll[t*10 + s - 1]*100);
                    const float* xp = isKL ? sVKl : (xq + q*100);
                    #pragma unroll
                    for (int jj = 0; jj < 7; ++jj) {
                        int k = k0 + 16*jj;
                        if (k < 100) acc = fmaf(st[k], xp[k], acc);
                    }
                }
            }
            acc += __shfl_xor(acc, 1); acc += __shfl_xor(acc, 2);
            acc += __shfl_xor(acc, 4); acc += __shfl_xor(acc, 8);
            if (on && k0 == 0) { if (isKL) sKL[s] = acc + ck; else sGv[q*11 + s] = acc; }
        }
        __syncthreads();
        // -------- softmax + output --------
        if (tid < 64) {
            int nst = nv + 1;
            int q = tid / 11, s = tid - q*11;
            bool valid = (tid < 55) && (s < nst);
            float lg = valid ? (sQLall[t*8 + q] + sKL[s] + bw) : -3.0e38f;
            float mx = lg;
            #pragma unroll
            for (int m = 1; m < 64; m <<= 1) mx = fmaxf(mx, __shfl_xor(mx, m));
            float e  = valid ? __expf(lg - mx) : 0.f;
            float gv = valid ? sGv[q*11 + s] : 0.f;
            float se = e, sg = e*gv;
            #pragma unroll
            for (int m = 1; m < 64; m <<= 1) { se += __shfl_xor(se, m); sg += __shfl_xor(sg, m); }
            if (tid == 0) out[b*TT + t + 1] = __fdividef(1.f, 1.f + __expf(-__fdividef(sg, se)));
        }
        gpre = gpre_nx;
        __syncthreads();
    }
}

extern "C" void kernel_launch(void* const* d_in, const int* in_sizes, int n_in,
                              void* d_out, int out_size, void* d_ws, size_t ws_size,
                              hipStream_t stream) {
    const int* user      = (const int*)d_in[0];
    const int* question  = (const int*)d_in[1];
    const int* response  = (const int*)d_in[2];
    const int* mask      = (const int*)d_in[3];
    const int* qnbr      = (const int*)d_in[4];
    const int* snbr      = (const int*)d_in[5];
    const int* unbr      = (const int*)d_in[6];
    const int* qnbr2     = (const int*)d_in[7];
    const int* qsidx     = (const int*)d_in[8];
    const float* embQ    = (const float*)d_in[9];
    const float* embQ2   = (const float*)d_in[10];
    const float* embS    = (const float*)d_in[11];
    const float* embU    = (const float*)d_in[12];
    const float* embR    = (const float*)d_in[13];
    const float* w1      = (const float*)d_in[14];
    const float* w2      = (const float*)d_in[15];
    const float* wih     = (const float*)d_in[16];
    const float* whh     = (const float*)d_in[17];
    const float* bih     = (const float*)d_in[18];
    const float* bhh     = (const float*)d_in[19];
    const float* aggw    = (const float*)d_in[20];
    const float* aggb    = (const float*)d_in[21];
    const float* wlast   = (const float*)d_in[22];
    const float* blast   = (const float*)d_in[23];
    const float* wq      = (const float*)d_in[24];
    const float* bq      = (const float*)d_in[25];
    const float* wk      = (const float*)d_in[26];
    const float* bk      = (const float*)d_in[27];
    const float* ww      = (const float*)d_in[28];
    const float* bwp     = (const float*)d_in[29];
    const float* wfus    = (const float*)d_in[30];
    const float* bfus    = (const float*)d_in[31];
    float* WS = (float*)d_ws;
    float* out = (float*)d_out;

    hipLaunchKernelGGL(kprep, dim3(1), dim3(256), 0, stream,
                       wq, bq, wk, bk, ww, bwp, w1, w2, bih, bhh, WS);
    hipLaunchKernelGGL(kagg, dim3(2*BSZ*TS), dim3(256), 0, stream,
                       user, question, mask, qnbr, snbr, unbr, qnbr2,
                       embQ, embQ2, embS, embU, aggw, aggb, wlast, blast, WS);
    hipLaunchKernelGGL(kfuse, dim3(BSZ*TS), dim3(256), 0, stream,
                       question, response, qsidx, embQ, embS, embR,
                       wfus, bfus, wih, WS);
    hipLaunchKernelGGL(kseq, dim3(BSZ), dim3(512), 0, stream,
                       mask, whh, WS, out);
}

// Round 5
// 438.385 us; speedup vs baseline: 1.9451x; 1.1160x over previous
//
#include <hip/hip_runtime.h>
#include <hip/hip_bf16.h>

#define BSZ 32
#define TT 50
#define TS 49
#define PH 101   // sSH pitch (odd -> conflict-free scattered row reads)

// ---- ws layout (float offsets) ----
#define OFF_GPRE  0u         // 32*49*400 = 627200
#define OFF_QL    627200u    // 32*49*8   = 12544  -> 639744
#define OFF_IDX   639744u    // 32*49*10 ints     -> 655424
#define OFF_NV    655424u    // 32*49 ints        -> 656992
#define OFF_QSC   656992u    // 32*49*500         -> 1440992
#define OFF_E1    1440992u   // 32*49*100         -> 1597792
#define OFF_E2    1597792u   // 32*49*100         -> 1754592 (~7.02 MB)

#define RLF(v,l) __uint_as_float(__builtin_amdgcn_readlane(__float_as_uint(v), (l)))

__device__ __forceinline__ float tanh_fast(float x) {
    float e = __expf(2.f * x);
    return 1.f - __fdividef(2.f, e + 1.f);
}
__device__ __forceinline__ float sigm_fast(float x) {
    return __fdividef(1.f, 1.f + __expf(-x));
}
__device__ __forceinline__ float dot4(float4 a, float4 b) {
    return a.x*b.x + a.y*b.y + a.z*b.z + a.w*b.w;
}
__device__ __forceinline__ float dot100(const float* __restrict__ w, const float* __restrict__ x) {
    float acc = 0.f;
    for (int k = 0; k < 100; k += 4)
        acc += dot4(*(const float4*)(w + k), *(const float4*)(x + k));
    return acc;
}

// ---------------- one aggregate per block, 384 threads ----------------
__global__ __launch_bounds__(384, 5) void kagg(
    const int* __restrict__ user, const int* __restrict__ question, const int* __restrict__ mask,
    const int* __restrict__ qnbr, const int* __restrict__ snbr,
    const int* __restrict__ unbr, const int* __restrict__ qnbr2,
    const float* __restrict__ embQ, const float* __restrict__ embQ2, const float* __restrict__ embS,
    const float* __restrict__ embU,
    const float* __restrict__ aggw, const float* __restrict__ aggb,
    const float* __restrict__ wlast, const float* __restrict__ blast,
    float* __restrict__ WS)
{
    int bid = blockIdx.x;
    int pair = bid >> 1, which = bid & 1;
    int b = pair / TS, t = pair - b*TS;
    int tid = threadIdx.x;
    int mm = mask[b*TT + t];
    float* outE = WS + (which ? OFF_E2 : OFF_E1) + (size_t)pair*100;

    if (mm != 1) {
        int q_t = question[b*TT + t];
        const float* src = which ? embQ2 : embQ;
        if (tid < 100) outE[tid] = src[(size_t)q_t*100 + tid];
        return;
    }

    int root = which ? user[b*TT + t] : question[b*TT + t];
    const int*   tabA = which ? unbr  : qnbr;
    const int*   tabB = which ? qnbr2 : snbr;
    const float* embE = which ? embU  : embQ;
    const float* embO = which ? embQ2 : embS;

    __shared__ __align__(16) float b2in[36*108];
    __shared__ __align__(16) float x1[6*108];
    __shared__ float s2v1b[600];        // s2 in i=0, v1b in i=1 (disjoint lifetimes)
    __shared__ float v1a[600];
    __shared__ __align__(16) float x0[104], v0a[104], v0b[104];
    __shared__ int n1[8], n2[36], n3[216];

    if (tid < 6) n1[tid] = tabA[root*6 + tid];
    __syncthreads();
    if (tid < 36) n2[tid] = tabB[n1[tid/6]*6 + (tid % 6)];
    __syncthreads();
    if (tid < 216) n3[tid] = tabA[n2[tid/6]*6 + (tid % 6)];
    __syncthreads();
    // ---- stage hop inputs ----
    for (int e = tid; e < 3600; e += 384) {
        int v = e / 100, d = e - v*100;
        float acc = embE[(size_t)n2[v]*100 + d];
        float s3 = 0.f;
        const int* p = n3 + v*6;
        for (int c = 0; c < 6; ++c) s3 += embO[(size_t)p[c]*100 + d];
        b2in[v*108 + d] = acc + s3 * (1.f/6.f);
    }
    for (int e = tid; e < 600; e += 384) {
        int a = e / 100, d = e - a*100;
        float acc = embO[(size_t)n1[a]*100 + d];
        float s = 0.f;
        for (int c = 0; c < 6; ++c) s += embE[(size_t)n2[a*6 + c]*100 + d];
        x1[a*108 + d] = acc + s * (1.f/6.f);
    }
    if (tid < 100) {
        float acc = embE[(size_t)root*100 + tid];
        float s = 0.f;
        for (int a = 0; a < 6; ++a) s += embO[(size_t)n1[a]*100 + tid];
        x0[tid] = acc + s * (1.f/6.f);
    }
    __syncthreads();
    // ---- i=0: j=2 (tid<300: 2 rows x 6 cols), j=1 (300-349: 2x6), j=0 (350-374: 4 rows) ----
    if (tid < 300) {
        int dblk = tid / 6, a = tid - dblk*6, d0 = dblk*2;
        const float* wp = aggw + 20000 + d0*100;
        const float* xb = b2in + a*648;
        float a0[6], a1[6];
        #pragma unroll
        for (int c = 0; c < 6; ++c) { a0[c] = 0.f; a1[c] = 0.f; }
        #pragma unroll
        for (int j = 0; j < 25; ++j) {
            float4 r0 = *(const float4*)(wp + 4*j);
            float4 r1 = *(const float4*)(wp + 100 + 4*j);
            #pragma unroll
            for (int c = 0; c < 6; ++c) {
                float4 x = *(const float4*)(xb + c*108 + 4*j);
                a0[c] += dot4(r0, x);
                a1[c] += dot4(r1, x);
            }
        }
        float bi0 = aggb[200 + d0], bi1 = aggb[200 + d0 + 1];
        float o0 = 0.f, o1 = 0.f;
        #pragma unroll
        for (int c = 0; c < 6; ++c) { o0 += tanh_fast(bi0 + a0[c]); o1 += tanh_fast(bi1 + a1[c]); }
        s2v1b[a*100 + d0] = o0; s2v1b[a*100 + d0 + 1] = o1;
    } else if (tid < 350) {
        int d0 = (tid - 300)*2;
        const float* wp = aggw + 10000 + d0*100;
        float a0[6], a1[6];
        #pragma unroll
        for (int c = 0; c < 6; ++c) { a0[c] = 0.f; a1[c] = 0.f; }
        #pragma unroll
        for (int j = 0; j < 25; ++j) {
            float4 r0 = *(const float4*)(wp + 4*j);
            float4 r1 = *(const float4*)(wp + 100 + 4*j);
            #pragma unroll
            for (int c = 0; c < 6; ++c) {
                float4 x = *(const float4*)(x1 + c*108 + 4*j);
                a0[c] += dot4(r0, x);
                a1[c] += dot4(r1, x);
            }
        }
        #pragma unroll
        for (int c = 0; c < 6; ++c) {
            v1a[c*100 + d0]     = tanh_fast(aggb[100 + d0] + a0[c]);
            v1a[c*100 + d0 + 1] = tanh_fast(aggb[100 + d0 + 1] + a1[c]);
        }
    } else if (tid < 375) {
        int d0 = (tid - 350)*4;
        const float* wp = aggw + d0*100;
        float a0 = 0.f, a1 = 0.f, a2 = 0.f, a3 = 0.f;
        #pragma unroll
        for (int j = 0; j < 25; ++j) {
            float4 x = *(const float4*)(x0 + 4*j);
            a0 += dot4(*(const float4*)(wp + 4*j), x);
            a1 += dot4(*(const float4*)(wp + 100 + 4*j), x);
            a2 += dot4(*(const float4*)(wp + 200 + 4*j), x);
            a3 += dot4(*(const float4*)(wp + 300 + 4*j), x);
        }
        v0a[d0]   = tanh_fast(aggb[d0] + a0);
        v0a[d0+1] = tanh_fast(aggb[d0+1] + a1);
        v0a[d0+2] = tanh_fast(aggb[d0+2] + a2);
        v0a[d0+3] = tanh_fast(aggb[d0+3] + a3);
    }
    __syncthreads();
    // ---- rebuild i=1 inputs ----
    for (int e = tid; e < 600; e += 384) {
        int a = e / 100, d = e - a*100;
        x1[a*108 + d] = v1a[a*100 + d] + s2v1b[a*100 + d]*(1.f/6.f);
    }
    if (tid < 100) {
        float s = 0.f;
        for (int a = 0; a < 6; ++a) s += v1a[a*100 + tid];
        x0[tid] = v0a[tid] + s*(1.f/6.f);
    }
    __syncthreads();
    // ---- i=1: j=1 (tid<50: 2x6 -> v1b), j=0 (tid 64-88: 4 rows -> v0b) ----
    if (tid < 50) {
        int d0 = tid*2;
        const float* wp = aggw + 10000 + d0*100;
        float a0[6], a1[6];
        #pragma unroll
        for (int c = 0; c < 6; ++c) { a0[c] = 0.f; a1[c] = 0.f; }
        #pragma unroll
        for (int j = 0; j < 25; ++j) {
            float4 r0 = *(const float4*)(wp + 4*j);
            float4 r1 = *(const float4*)(wp + 100 + 4*j);
            #pragma unroll
            for (int c = 0; c < 6; ++c) {
                float4 x = *(const float4*)(x1 + c*108 + 4*j);
                a0[c] += dot4(r0, x);
                a1[c] += dot4(r1, x);
            }
        }
        #pragma unroll
        for (int c = 0; c < 6; ++c) {
            s2v1b[c*100 + d0]     = tanh_fast(aggb[100 + d0] + a0[c]);
            s2v1b[c*100 + d0 + 1] = tanh_fast(aggb[100 + d0 + 1] + a1[c]);
        }
    } else if (tid >= 64 && tid < 89) {
        int d0 = (tid - 64)*4;
        const float* wp = aggw + d0*100;
        float a0 = 0.f, a1 = 0.f, a2 = 0.f, a3 = 0.f;
        #pragma unroll
        for (int j = 0; j < 25; ++j) {
            float4 x = *(const float4*)(x0 + 4*j);
            a0 += dot4(*(const float4*)(wp + 4*j), x);
            a1 += dot4(*(const float4*)(wp + 100 + 4*j), x);
            a2 += dot4(*(const float4*)(wp + 200 + 4*j), x);
            a3 += dot4(*(const float4*)(wp + 300 + 4*j), x);
        }
        v0b[d0]   = tanh_fast(aggb[d0] + a0);
        v0b[d0+1] = tanh_fast(aggb[d0+1] + a1);
        v0b[d0+2] = tanh_fast(aggb[d0+2] + a2);
        v0b[d0+3] = tanh_fast(aggb[d0+3] + a3);
    }
    __syncthreads();
    // ---- i=2 input ----
    if (tid < 100) {
        float s = 0.f;
        for (int a = 0; a < 6; ++a) s += s2v1b[a*100 + tid];
        x0[tid] = v0b[tid] + s*(1.f/6.f);
    }
    __syncthreads();
    if (tid < 25) {
        int d0 = tid*4;
        const float* wp = aggw + d0*100;
        float a0 = 0.f, a1 = 0.f, a2 = 0.f, a3 = 0.f;
        #pragma unroll
        for (int j = 0; j < 25; ++j) {
            float4 x = *(const float4*)(x0 + 4*j);
            a0 += dot4(*(const float4*)(wp + 4*j), x);
            a1 += dot4(*(const float4*)(wp + 100 + 4*j), x);
            a2 += dot4(*(const float4*)(wp + 200 + 4*j), x);
            a3 += dot4(*(const float4*)(wp + 300 + 4*j), x);
        }
        v0a[d0]   = tanh_fast(aggb[d0] + a0);
        v0a[d0+1] = tanh_fast(aggb[d0+1] + a1);
        v0a[d0+2] = tanh_fast(aggb[d0+2] + a2);
        v0a[d0+3] = tanh_fast(aggb[d0+3] + a3);
    }
    __syncthreads();
    if (tid < 25) {
        int d0 = tid*4;
        const float* wp = wlast + d0*100;
        float a0 = 0.f, a1 = 0.f, a2 = 0.f, a3 = 0.f;
        #pragma unroll
        for (int j = 0; j < 25; ++j) {
            float4 x = *(const float4*)(v0a + 4*j);
            a0 += dot4(*(const float4*)(wp + 4*j), x);
            a1 += dot4(*(const float4*)(wp + 100 + 4*j), x);
            a2 += dot4(*(const float4*)(wp + 200 + 4*j), x);
            a3 += dot4(*(const float4*)(wp + 300 + 4*j), x);
        }
        outE[d0]   = tanh_fast(blast[d0] + a0);
        outE[d0+1] = tanh_fast(blast[d0+1] + a1);
        outE[d0+2] = tanh_fast(blast[d0+2] + a2);
        outE[d0+3] = tanh_fast(blast[d0+3] + a3);
    }
}

// ---------------- fusion + GPRE + predict-side precompute (kprep inlined) ----------------
__global__ __launch_bounds__(256) void kfuse(
    const int* __restrict__ question, const int* __restrict__ response,
    const int* __restrict__ qsidx,
    const float* __restrict__ embQ, const float* __restrict__ embS, const float* __restrict__ embR,
    const float* __restrict__ w1p, const float* __restrict__ w2p,
    const float* __restrict__ wfus, const float* __restrict__ bfus,
    const float* __restrict__ wih, const float* __restrict__ bih, const float* __restrict__ bhh,
    const float* __restrict__ wq, const float* __restrict__ bq, const float* __restrict__ ww,
    float* __restrict__ WS)
{
    int bid = blockIdx.x;
    int b = bid / TS, t = bid - b*TS;
    int tid = threadIdx.x;
    size_t bt = (size_t)b*TS + t;

    __shared__ __align__(16) float sEIN[200], sET[104], sEQN[104], sVQ[104];
    __shared__ float sWW[200], sQSCm[500], sScore[56], sCq[1];

    int r_t = response[b*TT + t];
    int qn  = question[b*TT + t + 1];
    float w1 = w1p[0], w2 = w2p[0];
    // phase0
    if (tid < 100)
        sEIN[tid] = w1*WS[OFF_E1 + bt*100 + tid] + w2*WS[OFF_E2 + bt*100 + tid];
    else if (tid < 200)
        sEIN[tid] = embR[r_t*100 + (tid - 100)];
    else
        for (int i = tid - 200; i < 200; i += 56) sWW[i] = ww[i];
    __syncthreads();
    // phase1
    if (tid < 100) {
        float acc = bfus[tid];
        const float* wr = wfus + tid*200;
        for (int k = 0; k < 200; k += 4)
            acc += dot4(*(const float4*)(wr + k), *(const float4*)(sEIN + k));
        sET[tid] = fmaxf(acc, 0.f);
    } else if (tid < 200) {
        int k = tid - 100;
        float acc = 0.f;
        for (int d = 0; d < 100; ++d) acc += sWW[d]*wq[d*100 + k];
        sVQ[k] = acc;
    } else if (tid == 200) {
        float acc = 0.f;
        for (int d = 0; d < 100; ++d) acc += bq[d]*sWW[d];
        sCq[0] = acc;
    } else if (tid >= 201 && tid < 251) {
        int d = tid - 201;
        sEQN[d]      = embQ[(size_t)qn*100 + d];
        sEQN[d + 50] = embQ[(size_t)qn*100 + d + 50];
    }
    __syncthreads();
    // phase2
    if (tid < 200) {
        for (int i = tid; i < 500; i += 200) {
            int q = i / 100, d = i - q*100;
            float val = (q == 0) ? sEQN[d] : embS[(size_t)qsidx[qn*4 + (q-1)]*100 + d];
            sQSCm[i] = val;
            WS[OFF_QSC + bt*500 + i] = val;
        }
    } else if (tid < 250) {
        int tp = tid - 200;
        if (tp < t) {
            int qq = question[b*TT + tp];
            const float* er = embQ + (size_t)qq*100;
            float acc = 0.f;
            for (int k = 0; k < 100; k += 4)
                acc += dot4(*(const float4*)(er + k), *(const float4*)(sEQN + k));
            sScore[tp] = acc;
        }
    }
    __syncthreads();
    // phase3: GPRE + QL + topk
    for (int o = tid; o < 400; o += 256)
        WS[OFF_GPRE + bt*400 + o] = bih[o] + bhh[o] + dot100(wih + o*100, sET);
    if (tid < 80) {
        int q = tid >> 4, k0 = tid & 15;
        float acc = 0.f;
        #pragma unroll
        for (int j = 0; j < 7; ++j) {
            int k = k0 + 16*j;
            if (k < 100) acc = fmaf(sQSCm[q*100 + k], sVQ[k], acc);
        }
        acc += __shfl_xor(acc, 1); acc += __shfl_xor(acc, 2);
        acc += __shfl_xor(acc, 4); acc += __shfl_xor(acc, 8);
        if (k0 == 0) WS[OFF_QL + bt*8 + q] = acc + sCq[0];
    }
    if (tid == 255) {
        int nv = t < 10 ? t : 10;
        ((int*)(WS + OFF_NV))[bt] = nv;
        int* idxp = (int*)(WS + OFF_IDX) + bt*10;
        unsigned long long taken = 0ull;
        for (int p = 0; p < 10; ++p) {
            int bi = 0;
            if (p < nv) {
                float best = -3.0e38f;
                for (int tp2 = 0; tp2 < t; ++tp2) {
                    if (!((taken >> tp2) & 1ull) && sScore[tp2] > best) { best = sScore[tp2]; bi = tp2; }
                }
                taken |= (1ull << bi);
            }
            idxp[p] = bi;
        }
    }
}

// ---------------- sequential scan: 9 waves, 2 barriers/step ----------------
// waves 1-7: gates | wave 8: h-independent dots(t) | wave 0: tail of step t-1
__global__ __launch_bounds__(576) void kseq(
    const int* __restrict__ mask, const float* __restrict__ whh,
    const float* __restrict__ wk, const float* __restrict__ bk,
    const float* __restrict__ ww, const float* __restrict__ bwp,
    const float* __restrict__ WS, float* __restrict__ out)
{
    int b = blockIdx.x, tid = threadIdx.x, lane = tid & 63;
    __shared__ float sQSCall[TS*500];
    __shared__ float sSH[TS*PH + 3];
    __shared__ float sQLall[TS*8];
    __shared__ int   sIdxAll[TS*10];
    __shared__ int   sNvAll[TS];
    __shared__ int   sMask[TT];
    __shared__ float sH[104], sC[104], sG[400], sVKl[104];
    __shared__ float sKL2[2][12], sGv2[2][64];
    __shared__ float sCkBw[2];

    size_t b0 = (size_t)b*TS;
    int g = tid - 64;
    bool isGate = (g >= 0 && g < 400);

    float4 wv[25];
    if (isGate) {
        #pragma unroll
        for (int j = 0; j < 25; ++j) wv[j] = *(const float4*)(whh + g*100 + 4*j);
    }
    float gpre = isGate ? WS[OFF_GPRE + b0*400 + g] : 0.f;

    for (int i = tid; i < TS*500; i += 576) sQSCall[i] = WS[OFF_QSC + b0*500 + i];
    for (int i = tid; i < TS*8;   i += 576) sQLall[i]  = WS[OFF_QL + b0*8 + i];
    for (int i = tid; i < TS*10;  i += 576) sIdxAll[i] = ((const int*)(WS + OFF_IDX))[b0*10 + i];
    for (int i = tid; i < TS;     i += 576) sNvAll[i]  = ((const int*)(WS + OFF_NV))[b0 + i];
    if (tid < TT) sMask[tid] = mask[b*TT + tid];
    if (tid < 104) { sH[tid] = 0.f; sC[tid] = 0.f; }
    if (tid >= 104 && tid < 204) {
        int k = tid - 104;
        float acc = 0.f;
        for (int d = 0; d < 100; ++d) acc += ww[100 + d]*wk[d*100 + k];
        sVKl[k] = acc;
    }
    if (tid == 204) {
        float acc = 0.f;
        for (int d = 0; d < 100; ++d) acc += bk[d]*ww[100 + d];
        sCkBw[0] = acc; sCkBw[1] = bwp[0];
    }
    if (tid == 205) out[b*TT] = 0.5f;
    __syncthreads();
    float ck = sCkBw[0], bw = sCkBw[1];

    for (int t = 0; t < TS; ++t) {
        int par = t & 1;
        if (isGate) {
            // -------- gates(t): need h(t-1) = sH --------
            float hA = sH[lane];
            float hB = sH[64 + (lane % 36)];
            float gpre_nx = 0.f;
            if (t + 1 < TS) gpre_nx = WS[OFF_GPRE + (b0 + t + 1)*400 + g];
            float a0 = 0.f, a1 = 0.f, a2 = 0.f, a3 = 0.f;
            #pragma unroll
            for (int j = 0; j < 25; ++j) {
                const int kb = 4*j;
                float h0, h1, h2, h3;
                if (kb < 64) {
                    h0 = RLF(hA, kb);   h1 = RLF(hA, kb+1);
                    h2 = RLF(hA, kb+2); h3 = RLF(hA, kb+3);
                } else {
                    h0 = RLF(hB, kb-64); h1 = RLF(hB, kb-63);
                    h2 = RLF(hB, kb-62); h3 = RLF(hB, kb-61);
                }
                a0 = fmaf(h0, wv[j].x, a0);
                a1 = fmaf(h1, wv[j].y, a1);
                a2 = fmaf(h2, wv[j].z, a2);
                a3 = fmaf(h3, wv[j].w, a3);
            }
            sG[g] = (a0 + a1) + (a2 + a3) + gpre;
            gpre = gpre_nx;
        } else if (tid >= 512) {
            // -------- wave 8: 60 h-independent dots for step t --------
            int nv = sNvAll[t];
            if (lane < 60) {
                bool isKL = lane < 10;
                int s = isKL ? (lane + 1) : (((lane - 10) % 10) + 1);
                int q = isKL ? 0 : ((lane - 10) / 10);
                if (s <= nv) {
                    const float* st = sSH + sIdxAll[t*10 + s - 1]*PH;
                    const float* xp = isKL ? sVKl : (sQSCall + t*500 + q*100);
                    float c0 = 0.f, c1 = 0.f, c2 = 0.f, c3 = 0.f;
                    #pragma unroll
                    for (int k = 0; k < 100; k += 4) {
                        c0 = fmaf(st[k],   xp[k],   c0);
                        c1 = fmaf(st[k+1], xp[k+1], c1);
                        c2 = fmaf(st[k+2], xp[k+2], c2);
                        c3 = fmaf(st[k+3], xp[k+3], c3);
                    }
                    float acc = (c0 + c1) + (c2 + c3);
                    if (isKL) sKL2[par][s] = acc + ck;
                    else      sGv2[par][q*12 + s] = acc;
                }
            }
        } else if (tid < 64 && t > 0) {
            // -------- wave 0: tail of step tau = t-1 (h(tau) = sH, stable during A) --------
            int tau = t - 1, par2 = tau & 1;
            int nv = sNvAll[tau];
            int dd = lane >> 3, k0 = lane & 7;
            if (dd < 6) {
                const float* xp = (dd == 0) ? sVKl : (sQSCall + tau*500 + (dd-1)*100);
                float acc = 0.f;
                #pragma unroll
                for (int jj = 0; jj < 13; ++jj) {
                    int k = k0 + 8*jj;
                    if (k < 100) acc = fmaf(sH[k], xp[k], acc);
                }
                acc += __shfl_xor(acc, 1); acc += __shfl_xor(acc, 2); acc += __shfl_xor(acc, 4);
                if (k0 == 0) {
                    if (dd == 0) sKL2[par2][0] = acc + ck;
                    else         sGv2[par2][(dd-1)*12] = acc;
                }
            }
            int q = lane / 11, s = lane - q*11;
            bool valid = (lane < 55) && (s <= nv);
            float lg = valid ? (sQLall[tau*8 + q] + sKL2[par2][s] + bw) : 0.f;
            float e  = valid ? __expf(lg) : 0.f;   // |lg| small; no max-sub needed
            float gv = valid ? sGv2[par2][q*12 + s] : 0.f;
            float se = e, sg = e*gv;
            #pragma unroll
            for (int m = 1; m < 64; m <<= 1) { se += __shfl_xor(se, m); sg += __shfl_xor(sg, m); }
            if (lane == 0) out[b*TT + tau + 1] = __fdividef(1.f, 1.f + __expf(-__fdividef(sg, se)));
        }
        __syncthreads();
        // -------- LSTM pointwise --------
        if (g >= 0 && g < 100) {
            float gi = sG[g], gf = sG[100+g], gg = sG[200+g], go = sG[300+g];
            float c2 = sigm_fast(gf)*sC[g] + sigm_fast(gi)*tanh_fast(gg);
            float h2 = sigm_fast(go)*tanh_fast(c2);
            if (sMask[t] == 1) { sH[g] = h2; sC[g] = c2; }
            sSH[t*PH + g] = sH[g];
        }
        __syncthreads();
    }
    // -------- epilogue tail: tau = TS-1 --------
    if (tid < 64) {
        int tau = TS - 1, par2 = tau & 1;
        int nv = sNvAll[tau];
        int dd = lane >> 3, k0 = lane & 7;
        if (dd < 6) {
            const float* xp = (dd == 0) ? sVKl : (sQSCall + tau*500 + (dd-1)*100);
            float acc = 0.f;
            #pragma unroll
            for (int jj = 0; jj < 13; ++jj) {
                int k = k0 + 8*jj;
                if (k < 100) acc = fmaf(sH[k], xp[k], acc);
            }
            acc += __shfl_xor(acc, 1); acc += __shfl_xor(acc, 2); acc += __shfl_xor(acc, 4);
            if (k0 == 0) {
                if (dd == 0) sKL2[par2][0] = acc + ck;
                else         sGv2[par2][(dd-1)*12] = acc;
            }
        }
        int q = lane / 11, s = lane - q*11;
        bool valid = (lane < 55) && (s <= nv);
        float lg = valid ? (sQLall[tau*8 + q] + sKL2[par2][s] + bw) : 0.f;
        float e  = valid ? __expf(lg) : 0.f;
        float gv = valid ? sGv2[par2][q*12 + s] : 0.f;
        float se = e, sg = e*gv;
        #pragma unroll
        for (int m = 1; m < 64; m <<= 1) { se += __shfl_xor(se, m); sg += __shfl_xor(sg, m); }
        if (lane == 0) out[b*TT + tau + 1] = __fdividef(1.f, 1.f + __expf(-__fdividef(sg, se)));
    }
}

extern "C" void kernel_launch(void* const* d_in, const int* in_sizes, int n_in,
                              void* d_out, int out_size, void* d_ws, size_t ws_size,
                              hipStream_t stream) {
    const int* user      = (const int*)d_in[0];
    const int* question  = (const int*)d_in[1];
    const int* response  = (const int*)d_in[2];
    const int* mask      = (const int*)d_in[3];
    const int* qnbr      = (const int*)d_in[4];
    const int* snbr      = (const int*)d_in[5];
    const int* unbr      = (const int*)d_in[6];
    const int* qnbr2     = (const int*)d_in[7];
    const int* qsidx     = (const int*)d_in[8];
    const float* embQ    = (const float*)d_in[9];
    const float* embQ2   = (const float*)d_in[10];
    const float* embS    = (const float*)d_in[11];
    const float* embU    = (const float*)d_in[12];
    const float* embR    = (const float*)d_in[13];
    const float* w1      = (const float*)d_in[14];
    const float* w2      = (const float*)d_in[15];
    const float* wih     = (const float*)d_in[16];
    const float* whh     = (const float*)d_in[17];
    const float* bih     = (const float*)d_in[18];
    const float* bhh     = (const float*)d_in[19];
    const float* aggw    = (const float*)d_in[20];
    const float* aggb    = (const float*)d_in[21];
    const float* wlast   = (const float*)d_in[22];
    const float* blast   = (const float*)d_in[23];
    const float* wq      = (const float*)d_in[24];
    const float* bq      = (const float*)d_in[25];
    const float* wk      = (const float*)d_in[26];
    const float* bk      = (const float*)d_in[27];
    const float* ww      = (const float*)d_in[28];
    const float* bwp     = (const float*)d_in[29];
    const float* wfus    = (const float*)d_in[30];
    const float* bfus    = (const float*)d_in[31];
    float* WS = (float*)d_ws;
    float* out = (float*)d_out;

    hipLaunchKernelGGL(kagg, dim3(2*BSZ*TS), dim3(384), 0, stream,
                       user, question, mask, qnbr, snbr, unbr, qnbr2,
                       embQ, embQ2, embS, embU, aggw, aggb, wlast, blast, WS);
    hipLaunchKernelGGL(kfuse, dim3(BSZ*TS), dim3(256), 0, stream,
                       question, response, qsidx, embQ, embS, embR,
                       w1, w2, wfus, bfus, wih, bih, bhh, wq, bq, ww, WS);
    hipLaunchKernelGGL(kseq, dim3(BSZ), dim3(576), 0, stream,
                       mask, whh, wk, bk, ww, bwp, WS, out);
}